// Round 24
// baseline (3967.934 us; speedup 1.0000x reference)
//
#include <hip/hip_runtime.h>
#include <hip/hip_bf16.h>
#include <math.h>

// ---- model dims ----
#define BSZ 32
#define SEQ 1536
#define DM 256
#define NH 8
#define DH 32
#define MF 110
#define NL 6
#define RB (BSZ*SEQ)          // rows per stream = 49152
#define NCH 12
#define CH (SEQ/NCH)          // 128 rows per attention chunk
#define QKVW 768              // fused QKV row width

#define NRM 0.4204482076268573f         // 32^-0.25
#define HALF_NRM2 0.08838834764831845f  // 0.5/sqrt(32)
#define RATIO 0.09534625892455922f      // 110^-0.5
#define PEPS 1e-4f

typedef unsigned short u16;
using short8v = __attribute__((ext_vector_type(8))) short;
using f32x4   = __attribute__((ext_vector_type(4))) float;

#define GLOAD_LDS16(g, l) __builtin_amdgcn_global_load_lds( \
    (const __attribute__((address_space(1))) void*)(g), \
    (__attribute__((address_space(3))) void*)(l), 16, 0, 0)

__device__ __forceinline__ float wredsum(float v){
  #pragma unroll
  for (int o=32;o;o>>=1) v += __shfl_xor(v,o);
  return v;
}
__device__ __forceinline__ u16 f2bf(float x){
  unsigned u = __float_as_uint(x);
  return (u16)((u + 0x7FFFu + ((u>>16)&1u)) >> 16);
}
__device__ __forceinline__ float b2f(u16 h){
  return __uint_as_float(((unsigned)h)<<16);
}

// ---------------- sentinel ----------------
__global__ __launch_bounds__(256) void sentinel_k(float* __restrict__ out, int n, float v)
{
  int i = blockIdx.x*256 + threadIdx.x;
  if (i < n) out[i] = v;
}

// ---------------- zero helper ----------------
__global__ __launch_bounds__(256) void zero_k(float* __restrict__ p, int n)
{
  int i = blockIdx.x*256 + threadIdx.x;
  if (i < n) p[i] = 0.f;
}

// ---------------- weight transpose+convert: src fp32 [L][K][N] -> dst bf16 [L][N][K] ----------------
__global__ __launch_bounds__(256) void wtrans_k(
    const float* __restrict__ src, u16* __restrict__ dst,
    int K, int N, size_t dstStride)
{
  int l = blockIdx.z;
  const float* s = src + (size_t)l*K*N;
  u16* d = dst + (size_t)l*dstStride;
  __shared__ float t[32][33];
  int k0 = blockIdx.y*32, n0 = blockIdx.x*32;
  int tx = threadIdx.x & 31, ty = threadIdx.x >> 5;   // 32 x 8
  #pragma unroll
  for (int i=0;i<32;i+=8) t[ty+i][tx] = s[(size_t)(k0+ty+i)*N + n0+tx];
  __syncthreads();
  #pragma unroll
  for (int i=0;i<32;i+=8) d[(size_t)(n0+ty+i)*K + k0+tx] = f2bf(t[tx][ty+i]);
}

// ---------------- bias pack: bq|bk|bv -> [12][768] ----------------
__global__ __launch_bounds__(256) void bpack_k(
    const float* __restrict__ bq, const float* __restrict__ bk,
    const float* __restrict__ bv, float* __restrict__ dst)
{
  int l = blockIdx.x, t = threadIdx.x;
  dst[(size_t)l*QKVW + t]       = bq[(size_t)l*DM + t];
  dst[(size_t)l*QKVW + 256 + t] = bk[(size_t)l*DM + t];
  dst[(size_t)l*QKVW + 512 + t] = bv[(size_t)l*DM + t];
}

// ---------------- proj convert: fp32 [12][110][32] -> bf16 [12][112][32], NRM-prescaled, pad rows 0 ----
__global__ __launch_bounds__(256) void projcvt_k(
    const float* __restrict__ proj, u16* __restrict__ dst)
{
  int wi = blockIdx.x;
  for (int s = threadIdx.x; s < 112*32; s += 256){
    int m = s >> 5, dd = s & 31;
    float v = (m < MF) ? NRM*proj[(size_t)wi*MF*32 + (size_t)m*32 + dd] : 0.f;
    dst[(size_t)wi*112*32 + s] = f2bf(v);
  }
}

// ---------------- embed: build X (bf16) for one stream ----------------
__global__ __launch_bounds__(256) void embed_k(
    const float* __restrict__ mag, const float* __restrict__ syn,
    const float* __restrict__ magT, const float* __restrict__ synT,
    const float* __restrict__ se, const float* __restrict__ seT,
    u16* __restrict__ X, int s)
{
  int tid = threadIdx.x; int w = tid>>6; int lane = tid&63;
  int row = blockIdx.x*4 + w;
  int b = row / SEQ, t = row % SEQ;
  float val; const float* sep;
  if (!s) {
    int l = t / 192, c = t % 192;
    val = (c < 128) ? mag[((size_t)b*8 + l)*128 + c]
                    : syn[((size_t)b*8 + l)*64 + (c-128)];
    sep = se;
  } else {
    int r = t >> 3, l = t & 7;
    val = (r < 128) ? magT[((size_t)b*128 + r)*8 + l]
                    : synT[((size_t)b*64 + (r-128))*8 + l];
    sep = seT;
  }
  float4 e = *(const float4*)&sep[(size_t)t*DM + lane*4];
  ushort4 o;
  o.x = f2bf(val*e.x); o.y = f2bf(val*e.y);
  o.z = f2bf(val*e.z); o.w = f2bf(val*e.w);
  *(ushort4*)&X[(size_t)row*DM + lane*4] = o;
}

// ---------------- MFMA GEMM: 128x128 tile, 4 waves, XOR-swizzled LDS, XCD-chunked grid ----
// EPI: 0 -> bf16 out; 1 -> bf16 out (+R1 bf16); 2 -> bf16 out gelu; 3 -> bf16 out 0.5*(R1 + R2 + .)
__global__ __launch_bounds__(256) void mgemm_k(
    const u16* __restrict__ A, const u16* __restrict__ Wt,
    const float* __restrict__ bias, void* __restrict__ Cout,
    const void* __restrict__ R1, const void* __restrict__ R2,
    int K, int N, int EPI)
{
  __shared__ u16 As[128*32];   // [row][k] 64B rows, khalf-swizzled
  __shared__ u16 Bs[128*32];
  const int tid = threadIdx.x;
  const int lane = tid & 63, w = tid >> 6;
  const int wr = w >> 1, wc = w & 1;
  // XCD-chunked bijective swizzle (nwg % 8 == 0 for all launches)
  const int nwg = gridDim.x*gridDim.y;
  const int lin = blockIdx.y*gridDim.x + blockIdx.x;
  const int cpx = nwg >> 3;
  const int swz = (lin & 7)*cpx + (lin >> 3);
  const int bx = swz % gridDim.x, by = swz / gridDim.x;
  const int r0 = by*128, c0 = bx*128;

  f32x4 acc[4][4];
  #pragma unroll
  for (int m=0;m<4;m++){
    #pragma unroll
    for (int n=0;n<4;n++) acc[m][n] = (f32x4){0.f,0.f,0.f,0.f};
  }
  const int srow = lane >> 2;
  const int klog = (lane & 3) ^ ((srow >> 1) & 3);
  const int frow = lane & 15;
  const int rph  = (lane >> 4) ^ ((frow >> 1) & 3);

  for (int k0 = 0; k0 < K; k0 += 32){
    GLOAD_LDS16(&A [(size_t)(r0 + w*32      + srow)*K + k0 + klog*8], &As[(w*32     )*32]);
    GLOAD_LDS16(&A [(size_t)(r0 + w*32 + 16 + srow)*K + k0 + klog*8], &As[(w*32 + 16)*32]);
    GLOAD_LDS16(&Wt[(size_t)(c0 + w*32      + srow)*K + k0 + klog*8], &Bs[(w*32     )*32]);
    GLOAD_LDS16(&Wt[(size_t)(c0 + w*32 + 16 + srow)*K + k0 + klog*8], &Bs[(w*32 + 16)*32]);
    __syncthreads();
    short8v a[4], bq[4];
    #pragma unroll
    for (int m=0;m<4;m++)
      a[m] = *(const short8v*)&As[(wr*64 + m*16 + frow)*32 + rph*8];
    #pragma unroll
    for (int n=0;n<4;n++)
      bq[n] = *(const short8v*)&Bs[(wc*64 + n*16 + frow)*32 + rph*8];
    #pragma unroll
    for (int m=0;m<4;m++){
      #pragma unroll
      for (int n=0;n<4;n++)
        acc[m][n] = __builtin_amdgcn_mfma_f32_16x16x32_bf16(a[m], bq[n], acc[m][n], 0,0,0);
    }
    __syncthreads();
  }
  const int cb = c0 + wc*64 + (lane&15);
  const int rb = r0 + wr*64 + (lane>>4)*4;
  #pragma unroll
  for (int m=0;m<4;m++){
    #pragma unroll
    for (int n=0;n<4;n++){
      int c = cb + n*16;
      float bb = bias[c];
      #pragma unroll
      for (int i=0;i<4;i++){
        int r = rb + m*16 + i;
        size_t off = (size_t)r*N + c;
        float v = acc[m][n][i] + bb;
        if (EPI == 0) {
          ((u16*)Cout)[off] = f2bf(v);
        } else if (EPI == 1) {
          ((u16*)Cout)[off] = f2bf(v + b2f(((const u16*)R1)[off]));
        } else if (EPI == 2) {
          v = 0.5f*v*(1.f+erff(v*0.70710678118654752f));
          ((u16*)Cout)[off] = f2bf(v);
        } else {
          ((u16*)Cout)[off] = f2bf(0.5f*(b2f(((const u16*)R1)[off]) + b2f(((const u16*)R2)[off]) + v));
        }
      }
    }
  }
}

// ---------------- MFMA GEMM with fused row-LN on A: K=256 fixed, tile 128x128, A fully in LDS ----
// C = epi( LN(A_row) @ Wt^T + bias ).  EPI: 0 plain bf16; 2 gelu bf16.
__global__ __launch_bounds__(256) void mgemmlnA_k(
    const u16* __restrict__ A, const u16* __restrict__ Wt,
    const float* __restrict__ lsc, const float* __restrict__ lsb,
    const float* __restrict__ bias, u16* __restrict__ Cout,
    int N, int EPI)
{
  __shared__ u16 Af[128*256];   // [row][256k] 512B rows; within each 64B slice: khalf-swizzled
  __shared__ u16 Bs[128*32];
  __shared__ float mu_s[128], rs_s[128];
  __shared__ float sc_s[256], sb_s[256];
  const int tid = threadIdx.x;
  const int lane = tid & 63, w = tid >> 6;
  const int wr = w >> 1, wc = w & 1;
  const int nwg = gridDim.x*gridDim.y;
  const int lin = blockIdx.y*gridDim.x + blockIdx.x;
  const int cpx = nwg >> 3;
  const int swz = (lin & 7)*cpx + (lin >> 3);
  const int bx = swz % gridDim.x, by = swz / gridDim.x;
  const int r0 = by*128, c0 = bx*128;

  sc_s[tid] = lsc[tid];
  sb_s[tid] = lsb[tid];

  // stage full A-panel: wave w covers local rows [w*32, w*32+32), 2 rows per call
  {
    const int lrow_in = lane >> 5;          // 0/1 within pair
    const int l31 = lane & 31;
    const int sl = l31 >> 2;                // slice 0..7
    #pragma unroll
    for (int p = 0; p < 16; p++){
      int lrow = w*32 + p*2 + lrow_in;
      int kl = (l31 & 3) ^ ((lrow >> 1) & 3);
      GLOAD_LDS16(&A[(size_t)(r0 + lrow)*256 + sl*32 + kl*8], &Af[(size_t)(w*32 + p*2)*256]);
    }
  }
  __syncthreads();

  // row stats (two-pass, matches lnb semantics): thread pair (2 per row)
  {
    const int row = tid >> 1, half = tid & 1;
    float sum = 0.f;
    #pragma unroll
    for (int c=0;c<16;c++){
      short8v v = *(const short8v*)&Af[(size_t)row*256 + half*128 + c*8];
      #pragma unroll
      for (int j=0;j<8;j++) sum += b2f((u16)v[j]);
    }
    sum += __shfl_xor(sum, 1);
    float mu = sum * (1.f/256.f);
    float vs = 0.f;
    #pragma unroll
    for (int c=0;c<16;c++){
      short8v v = *(const short8v*)&Af[(size_t)row*256 + half*128 + c*8];
      #pragma unroll
      for (int j=0;j<8;j++){ float d = b2f((u16)v[j]) - mu; vs += d*d; }
    }
    vs += __shfl_xor(vs, 1);
    float rs = rsqrtf(vs*(1.f/256.f) + 1e-5f);
    if (half == 0){ mu_s[row] = mu; rs_s[row] = rs; }
    __syncthreads();
    // normalize in place (k recovered from swizzle)
    const float muv = mu_s[row], rsv = rs_s[row];
    const int swb = (row >> 1) & 3;
    #pragma unroll
    for (int c=0;c<16;c++){
      int off = half*128 + c*8;               // u16 within row
      int sl = off >> 5;
      int sp = (off >> 3) & 3;
      int kbase = sl*32 + (sp ^ swb)*8;
      short8v v = *(const short8v*)&Af[(size_t)row*256 + off];
      short8v o;
      #pragma unroll
      for (int j=0;j<8;j++){
        int k = kbase + j;
        o[j] = (short)f2bf((b2f((u16)v[j]) - muv)*rsv*sc_s[k] + sb_s[k]);
      }
      *(short8v*)&Af[(size_t)row*256 + off] = o;
    }
  }
  __syncthreads();

  f32x4 acc[4][4];
  #pragma unroll
  for (int m=0;m<4;m++){
    #pragma unroll
    for (int n=0;n<4;n++) acc[m][n] = (f32x4){0.f,0.f,0.f,0.f};
  }
  const int srow = lane >> 2;
  const int klog = (lane & 3) ^ ((srow >> 1) & 3);
  const int frow = lane & 15;
  const int rph  = (lane >> 4) ^ ((frow >> 1) & 3);

  for (int k0 = 0; k0 < 256; k0 += 32){
    GLOAD_LDS16(&Wt[(size_t)(c0 + w*32      + srow)*256 + k0 + klog*8], &Bs[(w*32     )*32]);
    GLOAD_LDS16(&Wt[(size_t)(c0 + w*32 + 16 + srow)*256 + k0 + klog*8], &Bs[(w*32 + 16)*32]);
    __syncthreads();
    short8v a[4], bq[4];
    #pragma unroll
    for (int m=0;m<4;m++)
      a[m] = *(const short8v*)&Af[(size_t)(wr*64 + m*16 + frow)*256 + k0 + rph*8];
    #pragma unroll
    for (int n=0;n<4;n++)
      bq[n] = *(const short8v*)&Bs[(wc*64 + n*16 + frow)*32 + rph*8];
    #pragma unroll
    for (int m=0;m<4;m++){
      #pragma unroll
      for (int n=0;n<4;n++)
        acc[m][n] = __builtin_amdgcn_mfma_f32_16x16x32_bf16(a[m], bq[n], acc[m][n], 0,0,0);
    }
    __syncthreads();
  }
  const int cb = c0 + wc*64 + (lane&15);
  const int rb = r0 + wr*64 + (lane>>4)*4;
  #pragma unroll
  for (int m=0;m<4;m++){
    #pragma unroll
    for (int n=0;n<4;n++){
      int c = cb + n*16;
      float bb = bias[c];
      #pragma unroll
      for (int i=0;i<4;i++){
        int r = rb + m*16 + i;
        size_t off = (size_t)r*N + c;
        float v = acc[m][n][i] + bb;
        if (EPI == 2) v = 0.5f*v*(1.f+erff(v*0.70710678118654752f));
        Cout[off] = f2bf(v);
      }
    }
  }
}

// ---------------- Performer K-side via MFMA: XD = K@projT; E^T@[V|1] with [E|1] augmentation ----
// part: bf16 [NCH][256][MF][36] (0-31 ctx-exp, 32 ksum-exp); stabb: f32 [NCH][256]
__global__ __launch_bounds__(256) void ctxacc_k(
    const u16* __restrict__ QKV, const u16* __restrict__ projb,
    u16* __restrict__ part, float* __restrict__ svb, float* __restrict__ stabb)
{
  const int h = blockIdx.x, b = blockIdx.y, ch = blockIdx.z;
  const int tid = threadIdx.x, w = tid>>6, lane = tid&63;
  const int bh = b*NH + h;
  const int l15 = lane & 15, g = lane >> 4;
  __shared__ __align__(16) u16 et_l[128*128];  // [m][r], slot-swizzled ^(m&15); rows 112..127 = pad (112=ones)
  __shared__ __align__(16) u16 vt_l[48*128];   // [d][r], slot-swizzled ^(d&15); row 32 = ones, 33..47 = 0
  __shared__ float red_l[4];

  const size_t pbase = ((size_t)ch*256 + bh)*MF*36;
  const size_t sbase = ((size_t)ch*256 + bh)*32;
  const u16* Kb = QKV + ((size_t)b*SEQ + ch*CH)*QKVW + 256 + h*32;
  const u16* Vb = QKV + ((size_t)b*SEQ + ch*CH)*QKVW + 512 + h*32;

  for (int u = tid; u < 512; u += 256){
    int r = u >> 2, d0 = (u & 3)*8;
    short8v vv = *(const short8v*)&Vb[(size_t)r*QKVW + d0];
    #pragma unroll
    for (int j=0;j<8;j++){
      int d = d0 + j;
      vt_l[d*128 + (((r>>3) ^ (d&15))<<3) + (r&7)] = (u16)vv[j];
    }
  }
  for (int e = tid; e < 16*128; e += 256){
    int d = 32 + (e>>7), r = e & 127;
    vt_l[d*128 + (((r>>3) ^ (d&15))<<3) + (r&7)] = (d==32) ? (u16)0x3F80 : (u16)0;
    int m = 112 + (e>>7);
    et_l[m*128 + (((r>>3) ^ (m&15))<<3) + (r&7)] = (m==112) ? (u16)0x3F80 : (u16)0;
  }

  short8v pf[7];
  #pragma unroll
  for (int j=0;j<7;j++)
    pf[j] = *(const short8v*)&projb[(j*16 + l15)*32 + g*8];
  f32x4 xd[2][7];
  float ssf[2];
  #pragma unroll
  for (int t=0;t<2;t++){
    short8v kf = *(const short8v*)&Kb[(size_t)(w*32 + t*16 + l15)*QKVW + g*8];
    float ss = 0.f;
    #pragma unroll
    for (int j=0;j<8;j++){ float q = b2f((u16)kf[j]); ss += q*q; }
    ss += __shfl_xor(ss, 16); ss += __shfl_xor(ss, 32);
    ssf[t] = ss;
    #pragma unroll
    for (int j=0;j<7;j++)
      xd[t][j] = __builtin_amdgcn_mfma_f32_16x16x32_bf16(kf, pf[j], (f32x4){0.f,0.f,0.f,0.f}, 0,0,0);
  }
  float mx = -1e30f;
  #pragma unroll
  for (int t=0;t<2;t++){
    #pragma unroll
    for (int j=0;j<7;j++){
      if (j==6 && l15 >= 14) continue;
      #pragma unroll
      for (int i=0;i<4;i++) mx = fmaxf(mx, xd[t][j][i]);
    }
  }
  #pragma unroll
  for (int o=32;o;o>>=1) mx = fmaxf(mx, __shfl_xor(mx,o));
  if (lane == 0) red_l[w] = mx;
  __syncthreads();
  const float stab = fmaxf(fmaxf(red_l[0],red_l[1]), fmaxf(red_l[2],red_l[3]));
  if (tid == 0) stabb[(size_t)ch*256 + bh] = stab;

  #pragma unroll
  for (int t=0;t<2;t++){
    int rbase = w*32 + t*16 + g*4;
    int slot = rbase >> 3;
    float dg[4];
    #pragma unroll
    for (int i=0;i<4;i++)
      dg[i] = HALF_NRM2 * __shfl(ssf[t], (lane & 48) | (g*4 + i));
    #pragma unroll
    for (int j=0;j<7;j++){
      int m = j*16 + l15;
      ushort4 pk;
      u16* pkp = &pk.x;
      #pragma unroll
      for (int i=0;i<4;i++){
        float e = (j==6 && l15>=14) ? 0.f : __expf(xd[t][j][i] - dg[i] - stab);
        pkp[i] = f2bf(e);
      }
      *(ushort4*)&et_l[m*128 + ((slot ^ (m&15))<<3) + (rbase & 7)] = pk;
    }
  }
  __syncthreads();

  #pragma unroll
  for (int mi=0; mi<2; mi++){
    int mt = w + mi*4;
    f32x4 a0 = (f32x4){0.f,0.f,0.f,0.f}, a1 = a0, a2 = a0;
    #pragma unroll
    for (int ks=0; ks<4; ks++){
      int sl = g + 4*ks;
      short8v ea = *(const short8v*)&et_l[(mt*16 + l15)*128 + ((sl ^ l15)<<3)];
      short8v v0 = *(const short8v*)&vt_l[(     l15)*128 + ((sl ^ l15)<<3)];
      short8v v1 = *(const short8v*)&vt_l[(16 + l15)*128 + ((sl ^ l15)<<3)];
      short8v v2 = *(const short8v*)&vt_l[(32 + l15)*128 + ((sl ^ l15)<<3)];
      a0 = __builtin_amdgcn_mfma_f32_16x16x32_bf16(ea, v0, a0, 0,0,0);
      a1 = __builtin_amdgcn_mfma_f32_16x16x32_bf16(ea, v1, a1, 0,0,0);
      a2 = __builtin_amdgcn_mfma_f32_16x16x32_bf16(ea, v2, a2, 0,0,0);
    }
    #pragma unroll
    for (int i=0;i<4;i++){
      int m = mt*16 + g*4 + i;
      if (m < MF){
        u16* pp = part + pbase + (size_t)m*36;
        pp[l15]      = f2bf(a0[i]);
        pp[16 + l15] = f2bf(a1[i]);
        if (l15 == 0) pp[32] = f2bf(a2[i]);
      } else if (m == 112){
        svb[sbase + l15]      = a0[i];
        svb[sbase + 16 + l15] = a1[i];
      }
    }
  }
}

// ---------------- reduce chunk partials -> ctxT (bf16 [bh][32][128]) + ksum (f32 [bh][112]) ----------------
__global__ __launch_bounds__(256) void ctxred_k(
    const u16* __restrict__ part, const float* __restrict__ svb,
    const float* __restrict__ stabb,
    u16* __restrict__ ctxTb, float* __restrict__ ksumg)
{
  int t = blockIdx.x*256 + threadIdx.x;   // t in [0, 256*MF*36)
  int d = t % 36;
  if (d >= 33) return;
  int bhm = t / 36;
  int bh = bhm / MF, m = bhm % MF;
  float gstab = -1e30f;
  float st[NCH];
  #pragma unroll
  for (int ch=0; ch<NCH; ch++){
    st[ch] = stabb[(size_t)ch*256 + bh];
    gstab = fmaxf(gstab, st[ch]);
  }
  float s = 0.f;
  #pragma unroll
  for (int ch=0; ch<NCH; ch++){
    size_t base = ((size_t)ch*256 + bh)*MF*36 + (size_t)m*36;
    s += b2f(part[base + d]) * __expf(st[ch] - gstab);
  }
  if (d < 32){
    float svtot = 0.f;
    #pragma unroll
    for (int ch=0; ch<NCH; ch++) svtot += svb[((size_t)ch*256 + bh)*32 + d];
    ctxTb[(size_t)bh*4096 + (size_t)d*128 + m] = f2bf(RATIO*(s + PEPS*svtot));
  } else {
    ksumg[(size_t)bh*112 + m] = RATIO*(s + PEPS*(float)SEQ);
  }
}

// ---------------- Performer O via MFMA: XD = Q@projT, softmax-phi, O = phi@ctxT ----------------
__global__ __launch_bounds__(256) void oattn_k(
    const u16* __restrict__ QKV, const u16* __restrict__ projb,
    const u16* __restrict__ ctxTb, const float* __restrict__ ksumg,
    u16* __restrict__ Og)
{
  const int blk = blockIdx.x, h = blockIdx.y, b = blockIdx.z;
  const int tid = threadIdx.x, wv = tid>>6, lane = tid&63;
  const int bh = b*NH + h;
  __shared__ __align__(16) u16 proj_l[112*40];   // [m][k], 80B rows
  __shared__ __align__(16) u16 ctx_l[32*136];    // [d][m], 272B rows (m>=110 zero)
  __shared__ float ksum_l[112];
  __shared__ float diag_l[4][16];
  __shared__ __align__(16) u16 phi_l[4][16*136]; // per-wave [row][m], 272B rows

  for (int s = tid; s < 448; s += 256){
    int r = s>>2, k8 = (s&3)*8;
    *(short8v*)&proj_l[r*40 + k8] = *(const short8v*)&projb[r*32 + k8];
  }
  for (int s = tid; s < 512; s += 256){
    int r = s>>4, m8 = (s&15)*8;
    *(short8v*)&ctx_l[r*136 + m8] = *(const short8v*)&ctxTb[(size_t)bh*4096 + r*128 + m8];
  }
  if (tid < 112) ksum_l[tid] = ksumg[(size_t)bh*112 + tid];
  for (int s = tid; s < 4*16*24; s += 256){
    int wvx = s/(16*24); int rem = s - wvx*16*24;
    phi_l[wvx][(rem/24)*136 + 112 + (rem%24)] = 0;
  }
  __syncthreads();

  const int l15 = lane & 15, g = lane >> 4;
  const u16* qbase = QKV + (size_t)b*SEQ*QKVW + h*32;
  const int rowblk = blk*256;

  for (int it = 0; it < 4; it++){
    const int r0 = rowblk + it*64 + wv*16;
    short8v qa = *(const short8v*)&qbase[(size_t)(r0 + l15)*QKVW + g*8];
    float ss = 0.f;
    #pragma unroll
    for (int j=0;j<8;j++){ float q = b2f((u16)qa[j]); ss += q*q; }
    ss += __shfl_xor(ss, 16); ss += __shfl_xor(ss, 32);
    if (lane < 16) diag_l[wv][lane] = HALF_NRM2 * ss;
    f32x4 xd[7];
    #pragma unroll
    for (int j=0;j<7;j++){
      short8v pf = *(const short8v*)&proj_l[(j*16 + l15)*40 + g*8];
      xd[j] = __builtin_amdgcn_mfma_f32_16x16x32_bf16(qa, pf, (f32x4){0.f,0.f,0.f,0.f}, 0,0,0);
    }
    float rden[4];
    #pragma unroll
    for (int i=0;i<4;i++){
      float mx = xd[0][i];
      #pragma unroll
      for (int j=1;j<7;j++) mx = fmaxf(mx, xd[j][i]);
      mx = fmaxf(mx, __shfl_xor(mx,1)); mx = fmaxf(mx, __shfl_xor(mx,2));
      mx = fmaxf(mx, __shfl_xor(mx,4)); mx = fmaxf(mx, __shfl_xor(mx,8));
      float dg = diag_l[wv][g*4+i];
      float dsum = 0.f;
      #pragma unroll
      for (int j=0;j<7;j++){
        float ph = RATIO*(__expf(xd[j][i] - dg - mx) + PEPS);
        xd[j][i] = ph;
        dsum += ph * ksum_l[l15 + 16*j];
      }
      dsum += __shfl_xor(dsum,1); dsum += __shfl_xor(dsum,2);
      dsum += __shfl_xor(dsum,4); dsum += __shfl_xor(dsum,8);
      rden[i] = 1.f / dsum;
      #pragma unroll
      for (int j=0;j<7;j++)
        phi_l[wv][(g*4+i)*136 + l15 + 16*j] = f2bf(xd[j][i]);
    }
    f32x4 o0 = (f32x4){0.f,0.f,0.f,0.f}, o1 = (f32x4){0.f,0.f,0.f,0.f};
    #pragma unroll
    for (int ks=0; ks<4; ks++){
      short8v af = *(const short8v*)&phi_l[wv][l15*136 + g*8 + ks*32];
      short8v b0 = *(const short8v*)&ctx_l[l15*136 + g*8 + ks*32];
      short8v b1 = *(const short8v*)&ctx_l[(16+l15)*136 + g*8 + ks*32];
      o0 = __builtin_amdgcn_mfma_f32_16x16x32_bf16(af, b0, o0, 0,0,0);
      o1 = __builtin_amdgcn_mfma_f32_16x16x32_bf16(af, b1, o1, 0,0,0);
    }
    u16* orow = Og + ((size_t)b*SEQ + r0)*DM + h*32;
    #pragma unroll
    for (int i=0;i<4;i++){
      int r = g*4 + i;
      orow[(size_t)r*DM + l15]      = f2bf(o0[i] * rden[i]);
      orow[(size_t)r*DM + 16 + l15] = f2bf(o1[i] * rden[i]);
    }
  }
}

// ---------------- z accumulation (X bf16) ----------------
__global__ __launch_bounds__(256) void zacc_k(
    const u16* __restrict__ X, const float* __restrict__ fw,
    const float* __restrict__ fb, float* __restrict__ Z, int mode)
{
  int tid=threadIdx.x, w=tid>>6, lane=tid&63;
  int row = blockIdx.x*4 + w;
  int b = row/SEQ, t = row%SEQ;
  int tt = t;
  if (mode == 1) {
    int l = t/192, r = t%192;
    tt = r*8 + l;
  }
  const ushort4 xh = *(const ushort4*)&X[((size_t)b*SEQ + tt)*DM + lane*4];
  const float4 f4 = *(const float4*)&fw[lane*4];
  float ssum = b2f(xh.x)*f4.x + b2f(xh.y)*f4.y + b2f(xh.z)*f4.z + b2f(xh.w)*f4.w;
  ssum = wredsum(ssum);
  if (lane==0) {
    if (mode == 0) Z[row] = ssum + fb[0];
    else           Z[row] += ssum;
  }
}

// ---------------- out = z @ out_w + out_b : grid (16, 32), 4-way t-split ----------------
__global__ __launch_bounds__(256) void out_k(
    const float* __restrict__ Z, const float* __restrict__ outw,
    const float* __restrict__ outb, float* __restrict__ out)
{
  const int c = blockIdx.x*64 + (threadIdx.x & 63);
  const int tg = threadIdx.x >> 6;            // 0..3
  const int b = blockIdx.y;
  __shared__ float zs[SEQ];
  __shared__ float red[4][64];
  for (int t = threadIdx.x; t < SEQ; t += 256) zs[t] = Z[(size_t)b*SEQ + t];
  __syncthreads();
  float acc = 0.f;
  const int t0 = tg*384;
  for (int t = t0; t < t0+384; t++) acc += zs[t] * outw[(size_t)t*1024 + c];
  red[tg][threadIdx.x & 63] = acc;
  __syncthreads();
  if (tg == 0)
    out[(size_t)b*1024 + c] = red[0][c & 63] + red[1][c & 63] + red[2][c & 63] + red[3][c & 63] + outb[c];
}

extern "C" void kernel_launch(void* const* d_in, const int* in_sizes, int n_in,
                              void* d_out, int out_size, void* d_ws, size_t ws_size,
                              hipStream_t stream) {
  (void)in_sizes; (void)n_in;
  const float* mag  = (const float*)d_in[0];
  const float* syn  = (const float*)d_in[1];
  const float* magT = (const float*)d_in[2];
  const float* synT = (const float*)d_in[3];
  const float* se   = (const float*)d_in[4];
  const float* seT  = (const float*)d_in[5];
  const float* ln1s = (const float*)d_in[6];
  const float* ln1b = (const float*)d_in[7];
  const float* Wq   = (const float*)d_in[8];
  const float* bq   = (const float*)d_in[9];
  const float* Wk   = (const float*)d_in[10];
  const float* bk   = (const float*)d_in[11];
  const float* Wv   = (const float*)d_in[12];
  const float* bv   = (const float*)d_in[13];
  const float* Wo   = (const float*)d_in[14];
  const float* bo   = (const float*)d_in[15];
  const float* proj = (const float*)d_in[16];
  const float* ln2s = (const float*)d_in[17];
  const float* ln2b = (const float*)d_in[18];
  const float* W1   = (const float*)d_in[19];
  const float* b1   = (const float*)d_in[20];
  const float* W2   = (const float*)d_in[21];
  const float* b2   = (const float*)d_in[22];
  const float* fw   = (const float*)d_in[23];
  const float* fb   = (const float*)d_in[24];
  const float* outw = (const float*)d_in[25];
  const float* outb = (const float*)d_in[26];
  float* out = (float*)d_out;

  // ---- workspace layout (bytes) ----
  char* base = (char*)d_ws;
  const size_t PANEL = (size_t)RB*DM;
  size_t off = 0;
  u16*  Xh    = (u16*)(base + off);   off += PANEL*4;           // X bf16 (slot kept 4B-sized)
  float* Y1   = (float*)(base + off); off += PANEL*4;           // Y1 bf16 (half); aliases PART during attention
  u16*  Hb    = (u16*)(base + off);   off += PANEL*2;
  u16*  QKVb  = (u16*)(base + off);   off += PANEL*2*3;         // [RB][768]; also FFI [RB][512]
  u16*  Wts   = (u16*)(base + off);   off += (size_t)12*524288*2;
  u16*  CTXTb = (u16*)(base + off);   off += (size_t)256*4096*2;   // [bh][32][128] bf16
  float* KSb  = (float*)(base + off); off += (size_t)256*112*4;    // [bh][112] f32
  float* SVb  = (float*)(base + off); off += (size_t)NCH*256*32*4;
  float* STb  = (float*)(base + off); off += (size_t)NCH*256*4;    // per-chunk stab (f32)
  float* BQKV = (float*)(base + off); off += (size_t)12*QKVW*4;
  u16*  PROJB = (u16*)(base + off);   off += (size_t)12*112*32*2;
  float* Zb   = (float*)(base + off); off += (size_t)BSZ*SEQ*4;
  if (ws_size < off) {
    float v = 100000.0f + (float)(ws_size >> 20);
    sentinel_k<<<dim3((out_size+255)/256), 256, 0, stream>>>(out, out_size, v);
    return;
  }
  u16*  PARTb = (u16*)Y1;   // bf16 [NCH][256][MF][36] = 24.3 MB (Y1 dead during attention)
  u16*  Y1h   = (u16*)Y1;   // Y1 stored bf16 (25 MB of the 50 MB slot)
  const size_t WST = 524288;

  // ---- one-time prep: weights, biases, proj, zero ctxT/ksum pads ----
  wtrans_k<<<dim3(8,8,12),  256, 0, stream>>>(Wq, Wts + 0,      256, 256, WST);
  wtrans_k<<<dim3(8,8,12),  256, 0, stream>>>(Wk, Wts + 65536,  256, 256, WST);
  wtrans_k<<<dim3(8,8,12),  256, 0, stream>>>(Wv, Wts + 131072, 256, 256, WST);
  wtrans_k<<<dim3(8,8,12),  256, 0, stream>>>(Wo, Wts + 196608, 256, 256, WST);
  wtrans_k<<<dim3(16,8,12), 256, 0, stream>>>(W1, Wts + 262144, 256, 512, WST);
  wtrans_k<<<dim3(8,16,12), 256, 0, stream>>>(W2, Wts + 393216, 512, 256, WST);
  bpack_k<<<dim3(12), 256, 0, stream>>>(bq, bk, bv, BQKV);
  projcvt_k<<<dim3(12), 256, 0, stream>>>(proj, PROJB);
  zero_k<<<dim3((256*4096*2/4 + 255)/256), 256, 0, stream>>>((float*)CTXTb, 256*4096*2/4);
  zero_k<<<dim3((256*112 + 255)/256), 256, 0, stream>>>(KSb, 256*112);

  for (int s=0; s<2; s++){
    embed_k<<<dim3(RB/4), 256, 0, stream>>>(mag, syn, magT, synT, se, seT, Xh, s);
    for (int l=0; l<NL; l++){
      int wi = s*NL + l;
      const u16* Wqkvt = Wts + (size_t)wi*WST;          // [768][256] packed
      const u16* Wot = Wqkvt + 196608;
      const u16* W1t = Wqkvt + 262144;
      const u16* W2t = Wqkvt + 393216;
      const u16* pprojb = PROJB + (size_t)wi*112*32;

      // QKV = LN1(X) @ Wqkv + b   [LN fused into GEMM A-panel]
      mgemmlnA_k<<<dim3(6,384), 256, 0, stream>>>(Xh, Wqkvt,
          ln1s + (size_t)wi*DM, ln1b + (size_t)wi*DM,
          BQKV + (size_t)wi*QKVW, QKVb, QKVW, 0);
      ctxacc_k<<<dim3(NH,BSZ,NCH), 256, 0, stream>>>(QKVb, pprojb, PARTb, SVb, STb);
      ctxred_k<<<dim3(MF*36), 256, 0, stream>>>(PARTb, SVb, STb, CTXTb, KSb);
      oattn_k<<<dim3(SEQ/256, NH, BSZ), 256, 0, stream>>>(QKVb, pprojb, CTXTb, KSb, Hb);
      // Y1 = bf16(X + O@Wo + bo)
      mgemm_k<<<dim3(2,384), 256, 0, stream>>>(Hb, Wot, bo + (size_t)wi*DM, Y1h, Xh, nullptr, 256, 256, 1);
      // FFI = gelu(LN2(Y1) @ W1 + b1)   [LN fused]
      mgemmlnA_k<<<dim3(4,384), 256, 0, stream>>>(Y1h, W1t,
          ln2s + (size_t)wi*DM, ln2b + (size_t)wi*DM,
          b1 + (size_t)wi*512, QKVb, 512, 2);
      // X = bf16(0.5*(X + Y1 + FFI@W2 + b2))
      mgemm_k<<<dim3(2,384), 256, 0, stream>>>(QKVb, W2t, b2 + (size_t)wi*DM, Xh, Xh, Y1h, 512, 256, 3);
    }
    zacc_k<<<dim3(RB/4), 256, 0, stream>>>(Xh, fw, fb, Zb, s);
  }

  out_k<<<dim3(16, BSZ), 256, 0, stream>>>(Zb, outw, outb, out);
}

// Round 25
// 3073.365 us; speedup vs baseline: 1.2911x; 1.2911x over previous
//
#include <hip/hip_runtime.h>
#include <hip/hip_bf16.h>
#include <math.h>

// ---- model dims ----
#define BSZ 32
#define SEQ 1536
#define DM 256
#define NH 8
#define DH 32
#define MF 110
#define NL 6
#define RB (BSZ*SEQ)          // rows per stream = 49152
#define NCH 12
#define CH (SEQ/NCH)          // 128 rows per attention chunk
#define QKVW 768              // fused QKV row width

#define NRM 0.4204482076268573f         // 32^-0.25
#define HALF_NRM2 0.08838834764831845f  // 0.5/sqrt(32)
#define RATIO 0.09534625892455922f      // 110^-0.5
#define PEPS 1e-4f

typedef unsigned short u16;
using short8v = __attribute__((ext_vector_type(8))) short;
using f32x4   = __attribute__((ext_vector_type(4))) float;

#define GLOAD_LDS16(g, l) __builtin_amdgcn_global_load_lds( \
    (const __attribute__((address_space(1))) void*)(g), \
    (__attribute__((address_space(3))) void*)(l), 16, 0, 0)

__device__ __forceinline__ float wredsum(float v){
  #pragma unroll
  for (int o=32;o;o>>=1) v += __shfl_xor(v,o);
  return v;
}
__device__ __forceinline__ u16 f2bf(float x){
  unsigned u = __float_as_uint(x);
  return (u16)((u + 0x7FFFu + ((u>>16)&1u)) >> 16);
}
__device__ __forceinline__ float b2f(u16 h){
  return __uint_as_float(((unsigned)h)<<16);
}

// ---------------- sentinel ----------------
__global__ __launch_bounds__(256) void sentinel_k(float* __restrict__ out, int n, float v)
{
  int i = blockIdx.x*256 + threadIdx.x;
  if (i < n) out[i] = v;
}

// ---------------- zero helper ----------------
__global__ __launch_bounds__(256) void zero_k(float* __restrict__ p, int n)
{
  int i = blockIdx.x*256 + threadIdx.x;
  if (i < n) p[i] = 0.f;
}

// ---------------- weight transpose+convert: src fp32 [L][K][N] -> dst bf16 [L][N][K] ----------------
__global__ __launch_bounds__(256) void wtrans_k(
    const float* __restrict__ src, u16* __restrict__ dst,
    int K, int N, size_t dstStride)
{
  int l = blockIdx.z;
  const float* s = src + (size_t)l*K*N;
  u16* d = dst + (size_t)l*dstStride;
  __shared__ float t[32][33];
  int k0 = blockIdx.y*32, n0 = blockIdx.x*32;
  int tx = threadIdx.x & 31, ty = threadIdx.x >> 5;   // 32 x 8
  #pragma unroll
  for (int i=0;i<32;i+=8) t[ty+i][tx] = s[(size_t)(k0+ty+i)*N + n0+tx];
  __syncthreads();
  #pragma unroll
  for (int i=0;i<32;i+=8) d[(size_t)(n0+ty+i)*K + k0+tx] = f2bf(t[tx][ty+i]);
}

// ---------------- bias pack: bq|bk|bv -> [12][768] ----------------
__global__ __launch_bounds__(256) void bpack_k(
    const float* __restrict__ bq, const float* __restrict__ bk,
    const float* __restrict__ bv, float* __restrict__ dst)
{
  int l = blockIdx.x, t = threadIdx.x;
  dst[(size_t)l*QKVW + t]       = bq[(size_t)l*DM + t];
  dst[(size_t)l*QKVW + 256 + t] = bk[(size_t)l*DM + t];
  dst[(size_t)l*QKVW + 512 + t] = bv[(size_t)l*DM + t];
}

// ---------------- proj convert: fp32 [12][110][32] -> bf16 [12][112][32], NRM-prescaled, pad rows 0 ----
__global__ __launch_bounds__(256) void projcvt_k(
    const float* __restrict__ proj, u16* __restrict__ dst)
{
  int wi = blockIdx.x;
  for (int s = threadIdx.x; s < 112*32; s += 256){
    int m = s >> 5, dd = s & 31;
    float v = (m < MF) ? NRM*proj[(size_t)wi*MF*32 + (size_t)m*32 + dd] : 0.f;
    dst[(size_t)wi*112*32 + s] = f2bf(v);
  }
}

// ---------------- embed: build X (bf16) for one stream ----------------
__global__ __launch_bounds__(256) void embed_k(
    const float* __restrict__ mag, const float* __restrict__ syn,
    const float* __restrict__ magT, const float* __restrict__ synT,
    const float* __restrict__ se, const float* __restrict__ seT,
    u16* __restrict__ X, int s)
{
  int tid = threadIdx.x; int w = tid>>6; int lane = tid&63;
  int row = blockIdx.x*4 + w;
  int b = row / SEQ, t = row % SEQ;
  float val; const float* sep;
  if (!s) {
    int l = t / 192, c = t % 192;
    val = (c < 128) ? mag[((size_t)b*8 + l)*128 + c]
                    : syn[((size_t)b*8 + l)*64 + (c-128)];
    sep = se;
  } else {
    int r = t >> 3, l = t & 7;
    val = (r < 128) ? magT[((size_t)b*128 + r)*8 + l]
                    : synT[((size_t)b*64 + (r-128))*8 + l];
    sep = seT;
  }
  float4 e = *(const float4*)&sep[(size_t)t*DM + lane*4];
  ushort4 o;
  o.x = f2bf(val*e.x); o.y = f2bf(val*e.y);
  o.z = f2bf(val*e.z); o.w = f2bf(val*e.w);
  *(ushort4*)&X[(size_t)row*DM + lane*4] = o;
}

// ---------------- LayerNorm: bf16 in -> bf16 out ----------------
__global__ __launch_bounds__(256) void lnb_k(
    const u16* __restrict__ in, u16* __restrict__ out,
    const float* __restrict__ sc, const float* __restrict__ sb)
{
  int tid=threadIdx.x, w=tid>>6, lane=tid&63;
  size_t row = (size_t)blockIdx.x*4 + w;
  const ushort4 h = *(const ushort4*)&in[row*DM + lane*4];
  float vx=b2f(h.x), vy=b2f(h.y), vz=b2f(h.z), vw=b2f(h.w);
  float sum = vx+vy+vz+vw;
  sum = wredsum(sum);
  float mu = sum * (1.f/256.f);
  float dx=vx-mu, dy=vy-mu, dz=vz-mu, dw=vw-mu;
  float vs = dx*dx+dy*dy+dz*dz+dw*dw;
  vs = wredsum(vs);
  float rstd = rsqrtf(vs*(1.f/256.f) + 1e-5f);
  float4 s4 = *(const float4*)&sc[lane*4];
  float4 b4 = *(const float4*)&sb[lane*4];
  ushort4 o;
  o.x = f2bf(dx*rstd*s4.x+b4.x); o.y = f2bf(dy*rstd*s4.y+b4.y);
  o.z = f2bf(dz*rstd*s4.z+b4.z); o.w = f2bf(dw*rstd*s4.w+b4.w);
  *(ushort4*)&out[row*DM + lane*4] = o;
}

// ---------------- MFMA GEMM: 128x128 tile, 4 waves, XOR-swizzled LDS, XCD-chunked grid ----
// EPI: 0 -> bf16 out; 1 -> bf16 out (+R1 bf16); 2 -> bf16 out gelu; 3 -> bf16 out 0.5*(R1 + R2 + .)
__global__ __launch_bounds__(256) void mgemm_k(
    const u16* __restrict__ A, const u16* __restrict__ Wt,
    const float* __restrict__ bias, void* __restrict__ Cout,
    const void* __restrict__ R1, const void* __restrict__ R2,
    int K, int N, int EPI)
{
  __shared__ u16 As[128*32];   // [row][k] 64B rows, khalf-swizzled
  __shared__ u16 Bs[128*32];
  const int tid = threadIdx.x;
  const int lane = tid & 63, w = tid >> 6;
  const int wr = w >> 1, wc = w & 1;
  // XCD-chunked bijective swizzle (nwg % 8 == 0 for all launches)
  const int nwg = gridDim.x*gridDim.y;
  const int lin = blockIdx.y*gridDim.x + blockIdx.x;
  const int cpx = nwg >> 3;
  const int swz = (lin & 7)*cpx + (lin >> 3);
  const int bx = swz % gridDim.x, by = swz / gridDim.x;
  const int r0 = by*128, c0 = bx*128;

  f32x4 acc[4][4];
  #pragma unroll
  for (int m=0;m<4;m++){
    #pragma unroll
    for (int n=0;n<4;n++) acc[m][n] = (f32x4){0.f,0.f,0.f,0.f};
  }
  const int srow = lane >> 2;
  const int klog = (lane & 3) ^ ((srow >> 1) & 3);
  const int frow = lane & 15;
  const int rph  = (lane >> 4) ^ ((frow >> 1) & 3);

  for (int k0 = 0; k0 < K; k0 += 32){
    GLOAD_LDS16(&A [(size_t)(r0 + w*32      + srow)*K + k0 + klog*8], &As[(w*32     )*32]);
    GLOAD_LDS16(&A [(size_t)(r0 + w*32 + 16 + srow)*K + k0 + klog*8], &As[(w*32 + 16)*32]);
    GLOAD_LDS16(&Wt[(size_t)(c0 + w*32      + srow)*K + k0 + klog*8], &Bs[(w*32     )*32]);
    GLOAD_LDS16(&Wt[(size_t)(c0 + w*32 + 16 + srow)*K + k0 + klog*8], &Bs[(w*32 + 16)*32]);
    __syncthreads();
    short8v a[4], bq[4];
    #pragma unroll
    for (int m=0;m<4;m++)
      a[m] = *(const short8v*)&As[(wr*64 + m*16 + frow)*32 + rph*8];
    #pragma unroll
    for (int n=0;n<4;n++)
      bq[n] = *(const short8v*)&Bs[(wc*64 + n*16 + frow)*32 + rph*8];
    #pragma unroll
    for (int m=0;m<4;m++){
      #pragma unroll
      for (int n=0;n<4;n++)
        acc[m][n] = __builtin_amdgcn_mfma_f32_16x16x32_bf16(a[m], bq[n], acc[m][n], 0,0,0);
    }
    __syncthreads();
  }
  const int cb = c0 + wc*64 + (lane&15);
  const int rb = r0 + wr*64 + (lane>>4)*4;
  #pragma unroll
  for (int m=0;m<4;m++){
    #pragma unroll
    for (int n=0;n<4;n++){
      int c = cb + n*16;
      float bb = bias[c];
      #pragma unroll
      for (int i=0;i<4;i++){
        int r = rb + m*16 + i;
        size_t off = (size_t)r*N + c;
        float v = acc[m][n][i] + bb;
        if (EPI == 0) {
          ((u16*)Cout)[off] = f2bf(v);
        } else if (EPI == 1) {
          ((u16*)Cout)[off] = f2bf(v + b2f(((const u16*)R1)[off]));
        } else if (EPI == 2) {
          v = 0.5f*v*(1.f+erff(v*0.70710678118654752f));
          ((u16*)Cout)[off] = f2bf(v);
        } else {
          ((u16*)Cout)[off] = f2bf(0.5f*(b2f(((const u16*)R1)[off]) + b2f(((const u16*)R2)[off]) + v));
        }
      }
    }
  }
}

// ---------------- Performer K-side via MFMA: XD = K@projT; E^T@[V|1] with [E|1] augmentation ----
// part: bf16 [NCH][256][MF][36] (0-31 ctx-exp, 32 ksum-exp); stabb: f32 [NCH][256]
__global__ __launch_bounds__(256) void ctxacc_k(
    const u16* __restrict__ QKV, const u16* __restrict__ projb,
    u16* __restrict__ part, float* __restrict__ svb, float* __restrict__ stabb)
{
  const int h = blockIdx.x, b = blockIdx.y, ch = blockIdx.z;
  const int tid = threadIdx.x, w = tid>>6, lane = tid&63;
  const int bh = b*NH + h;
  const int l15 = lane & 15, g = lane >> 4;
  __shared__ __align__(16) u16 et_l[128*128];  // [m][r], slot-swizzled ^(m&15); rows 112..127 = pad (112=ones)
  __shared__ __align__(16) u16 vt_l[48*128];   // [d][r], slot-swizzled ^(d&15); row 32 = ones, 33..47 = 0
  __shared__ float red_l[4];

  const size_t pbase = ((size_t)ch*256 + bh)*MF*36;
  const size_t sbase = ((size_t)ch*256 + bh)*32;
  const u16* Kb = QKV + ((size_t)b*SEQ + ch*CH)*QKVW + 256 + h*32;
  const u16* Vb = QKV + ((size_t)b*SEQ + ch*CH)*QKVW + 512 + h*32;

  for (int u = tid; u < 512; u += 256){
    int r = u >> 2, d0 = (u & 3)*8;
    short8v vv = *(const short8v*)&Vb[(size_t)r*QKVW + d0];
    #pragma unroll
    for (int j=0;j<8;j++){
      int d = d0 + j;
      vt_l[d*128 + (((r>>3) ^ (d&15))<<3) + (r&7)] = (u16)vv[j];
    }
  }
  for (int e = tid; e < 16*128; e += 256){
    int d = 32 + (e>>7), r = e & 127;
    vt_l[d*128 + (((r>>3) ^ (d&15))<<3) + (r&7)] = (d==32) ? (u16)0x3F80 : (u16)0;
    int m = 112 + (e>>7);
    et_l[m*128 + (((r>>3) ^ (m&15))<<3) + (r&7)] = (m==112) ? (u16)0x3F80 : (u16)0;
  }

  short8v pf[7];
  #pragma unroll
  for (int j=0;j<7;j++)
    pf[j] = *(const short8v*)&projb[(j*16 + l15)*32 + g*8];
  f32x4 xd[2][7];
  float ssf[2];
  #pragma unroll
  for (int t=0;t<2;t++){
    short8v kf = *(const short8v*)&Kb[(size_t)(w*32 + t*16 + l15)*QKVW + g*8];
    float ss = 0.f;
    #pragma unroll
    for (int j=0;j<8;j++){ float q = b2f((u16)kf[j]); ss += q*q; }
    ss += __shfl_xor(ss, 16); ss += __shfl_xor(ss, 32);
    ssf[t] = ss;
    #pragma unroll
    for (int j=0;j<7;j++)
      xd[t][j] = __builtin_amdgcn_mfma_f32_16x16x32_bf16(kf, pf[j], (f32x4){0.f,0.f,0.f,0.f}, 0,0,0);
  }
  float mx = -1e30f;
  #pragma unroll
  for (int t=0;t<2;t++){
    #pragma unroll
    for (int j=0;j<7;j++){
      if (j==6 && l15 >= 14) continue;
      #pragma unroll
      for (int i=0;i<4;i++) mx = fmaxf(mx, xd[t][j][i]);
    }
  }
  #pragma unroll
  for (int o=32;o;o>>=1) mx = fmaxf(mx, __shfl_xor(mx,o));
  if (lane == 0) red_l[w] = mx;
  __syncthreads();
  const float stab = fmaxf(fmaxf(red_l[0],red_l[1]), fmaxf(red_l[2],red_l[3]));
  if (tid == 0) stabb[(size_t)ch*256 + bh] = stab;

  #pragma unroll
  for (int t=0;t<2;t++){
    int rbase = w*32 + t*16 + g*4;
    int slot = rbase >> 3;
    float dg[4];
    #pragma unroll
    for (int i=0;i<4;i++)
      dg[i] = HALF_NRM2 * __shfl(ssf[t], (lane & 48) | (g*4 + i));
    #pragma unroll
    for (int j=0;j<7;j++){
      int m = j*16 + l15;
      ushort4 pk;
      u16* pkp = &pk.x;
      #pragma unroll
      for (int i=0;i<4;i++){
        float e = (j==6 && l15>=14) ? 0.f : __expf(xd[t][j][i] - dg[i] - stab);
        pkp[i] = f2bf(e);
      }
      *(ushort4*)&et_l[m*128 + ((slot ^ (m&15))<<3) + (rbase & 7)] = pk;
    }
  }
  __syncthreads();

  #pragma unroll
  for (int mi=0; mi<2; mi++){
    int mt = w + mi*4;
    f32x4 a0 = (f32x4){0.f,0.f,0.f,0.f}, a1 = a0, a2 = a0;
    #pragma unroll
    for (int ks=0; ks<4; ks++){
      int sl = g + 4*ks;
      short8v ea = *(const short8v*)&et_l[(mt*16 + l15)*128 + ((sl ^ l15)<<3)];
      short8v v0 = *(const short8v*)&vt_l[(     l15)*128 + ((sl ^ l15)<<3)];
      short8v v1 = *(const short8v*)&vt_l[(16 + l15)*128 + ((sl ^ l15)<<3)];
      short8v v2 = *(const short8v*)&vt_l[(32 + l15)*128 + ((sl ^ l15)<<3)];
      a0 = __builtin_amdgcn_mfma_f32_16x16x32_bf16(ea, v0, a0, 0,0,0);
      a1 = __builtin_amdgcn_mfma_f32_16x16x32_bf16(ea, v1, a1, 0,0,0);
      a2 = __builtin_amdgcn_mfma_f32_16x16x32_bf16(ea, v2, a2, 0,0,0);
    }
    #pragma unroll
    for (int i=0;i<4;i++){
      int m = mt*16 + g*4 + i;
      if (m < MF){
        u16* pp = part + pbase + (size_t)m*36;
        pp[l15]      = f2bf(a0[i]);
        pp[16 + l15] = f2bf(a1[i]);
        if (l15 == 0) pp[32] = f2bf(a2[i]);
      } else if (m == 112){
        svb[sbase + l15]      = a0[i];
        svb[sbase + 16 + l15] = a1[i];
      }
    }
  }
}

// ---------------- reduce chunk partials -> ctxT (bf16 [bh][32][128]) + ksum (f32 [bh][112]) ----------------
__global__ __launch_bounds__(256) void ctxred_k(
    const u16* __restrict__ part, const float* __restrict__ svb,
    const float* __restrict__ stabb,
    u16* __restrict__ ctxTb, float* __restrict__ ksumg)
{
  int t = blockIdx.x*256 + threadIdx.x;   // t in [0, 256*MF*36)
  int d = t % 36;
  if (d >= 33) return;
  int bhm = t / 36;
  int bh = bhm / MF, m = bhm % MF;
  float gstab = -1e30f;
  float st[NCH];
  #pragma unroll
  for (int ch=0; ch<NCH; ch++){
    st[ch] = stabb[(size_t)ch*256 + bh];
    gstab = fmaxf(gstab, st[ch]);
  }
  float s = 0.f;
  #pragma unroll
  for (int ch=0; ch<NCH; ch++){
    size_t base = ((size_t)ch*256 + bh)*MF*36 + (size_t)m*36;
    s += b2f(part[base + d]) * __expf(st[ch] - gstab);
  }
  if (d < 32){
    float svtot = 0.f;
    #pragma unroll
    for (int ch=0; ch<NCH; ch++) svtot += svb[((size_t)ch*256 + bh)*32 + d];
    ctxTb[(size_t)bh*4096 + (size_t)d*128 + m] = f2bf(RATIO*(s + PEPS*svtot));
  } else {
    ksumg[(size_t)bh*112 + m] = RATIO*(s + PEPS*(float)SEQ);
  }
}

// ---------------- Performer O via MFMA: XD = Q@projT, softmax-phi, O = phi@ctxT ----------------
__global__ __launch_bounds__(256) void oattn_k(
    const u16* __restrict__ QKV, const u16* __restrict__ projb,
    const u16* __restrict__ ctxTb, const float* __restrict__ ksumg,
    u16* __restrict__ Og)
{
  const int blk = blockIdx.x, h = blockIdx.y, b = blockIdx.z;
  const int tid = threadIdx.x, wv = tid>>6, lane = tid&63;
  const int bh = b*NH + h;
  __shared__ __align__(16) u16 proj_l[112*40];   // [m][k], 80B rows
  __shared__ __align__(16) u16 ctx_l[32*136];    // [d][m], 272B rows (m>=110 zero)
  __shared__ float ksum_l[112];
  __shared__ float diag_l[4][16];
  __shared__ __align__(16) u16 phi_l[4][16*136]; // per-wave [row][m], 272B rows

  for (int s = tid; s < 448; s += 256){
    int r = s>>2, k8 = (s&3)*8;
    *(short8v*)&proj_l[r*40 + k8] = *(const short8v*)&projb[r*32 + k8];
  }
  for (int s = tid; s < 512; s += 256){
    int r = s>>4, m8 = (s&15)*8;
    *(short8v*)&ctx_l[r*136 + m8] = *(const short8v*)&ctxTb[(size_t)bh*4096 + r*128 + m8];
  }
  if (tid < 112) ksum_l[tid] = ksumg[(size_t)bh*112 + tid];
  for (int s = tid; s < 4*16*24; s += 256){
    int wvx = s/(16*24); int rem = s - wvx*16*24;
    phi_l[wvx][(rem/24)*136 + 112 + (rem%24)] = 0;
  }
  __syncthreads();

  const int l15 = lane & 15, g = lane >> 4;
  const u16* qbase = QKV + (size_t)b*SEQ*QKVW + h*32;
  const int rowblk = blk*256;

  for (int it = 0; it < 4; it++){
    const int r0 = rowblk + it*64 + wv*16;
    short8v qa = *(const short8v*)&qbase[(size_t)(r0 + l15)*QKVW + g*8];
    float ss = 0.f;
    #pragma unroll
    for (int j=0;j<8;j++){ float q = b2f((u16)qa[j]); ss += q*q; }
    ss += __shfl_xor(ss, 16); ss += __shfl_xor(ss, 32);
    if (lane < 16) diag_l[wv][lane] = HALF_NRM2 * ss;
    f32x4 xd[7];
    #pragma unroll
    for (int j=0;j<7;j++){
      short8v pf = *(const short8v*)&proj_l[(j*16 + l15)*40 + g*8];
      xd[j] = __builtin_amdgcn_mfma_f32_16x16x32_bf16(qa, pf, (f32x4){0.f,0.f,0.f,0.f}, 0,0,0);
    }
    float rden[4];
    #pragma unroll
    for (int i=0;i<4;i++){
      float mx = xd[0][i];
      #pragma unroll
      for (int j=1;j<7;j++) mx = fmaxf(mx, xd[j][i]);
      mx = fmaxf(mx, __shfl_xor(mx,1)); mx = fmaxf(mx, __shfl_xor(mx,2));
      mx = fmaxf(mx, __shfl_xor(mx,4)); mx = fmaxf(mx, __shfl_xor(mx,8));
      float dg = diag_l[wv][g*4+i];
      float dsum = 0.f;
      #pragma unroll
      for (int j=0;j<7;j++){
        float ph = RATIO*(__expf(xd[j][i] - dg - mx) + PEPS);
        xd[j][i] = ph;
        dsum += ph * ksum_l[l15 + 16*j];
      }
      dsum += __shfl_xor(dsum,1); dsum += __shfl_xor(dsum,2);
      dsum += __shfl_xor(dsum,4); dsum += __shfl_xor(dsum,8);
      rden[i] = 1.f / dsum;
      #pragma unroll
      for (int j=0;j<7;j++)
        phi_l[wv][(g*4+i)*136 + l15 + 16*j] = f2bf(xd[j][i]);
    }
    f32x4 o0 = (f32x4){0.f,0.f,0.f,0.f}, o1 = (f32x4){0.f,0.f,0.f,0.f};
    #pragma unroll
    for (int ks=0; ks<4; ks++){
      short8v af = *(const short8v*)&phi_l[wv][l15*136 + g*8 + ks*32];
      short8v b0 = *(const short8v*)&ctx_l[l15*136 + g*8 + ks*32];
      short8v b1 = *(const short8v*)&ctx_l[(16+l15)*136 + g*8 + ks*32];
      o0 = __builtin_amdgcn_mfma_f32_16x16x32_bf16(af, b0, o0, 0,0,0);
      o1 = __builtin_amdgcn_mfma_f32_16x16x32_bf16(af, b1, o1, 0,0,0);
    }
    u16* orow = Og + ((size_t)b*SEQ + r0)*DM + h*32;
    #pragma unroll
    for (int i=0;i<4;i++){
      int r = g*4 + i;
      orow[(size_t)r*DM + l15]      = f2bf(o0[i] * rden[i]);
      orow[(size_t)r*DM + 16 + l15] = f2bf(o1[i] * rden[i]);
    }
  }
}

// ---------------- z accumulation (X bf16) ----------------
__global__ __launch_bounds__(256) void zacc_k(
    const u16* __restrict__ X, const float* __restrict__ fw,
    const float* __restrict__ fb, float* __restrict__ Z, int mode)
{
  int tid=threadIdx.x, w=tid>>6, lane=tid&63;
  int row = blockIdx.x*4 + w;
  int b = row/SEQ, t = row%SEQ;
  int tt = t;
  if (mode == 1) {
    int l = t/192, r = t%192;
    tt = r*8 + l;
  }
  const ushort4 xh = *(const ushort4*)&X[((size_t)b*SEQ + tt)*DM + lane*4];
  const float4 f4 = *(const float4*)&fw[lane*4];
  float ssum = b2f(xh.x)*f4.x + b2f(xh.y)*f4.y + b2f(xh.z)*f4.z + b2f(xh.w)*f4.w;
  ssum = wredsum(ssum);
  if (lane==0) {
    if (mode == 0) Z[row] = ssum + fb[0];
    else           Z[row] += ssum;
  }
}

// ---------------- out = z @ out_w + out_b : grid (16, 32), 4-way t-split ----------------
__global__ __launch_bounds__(256) void out_k(
    const float* __restrict__ Z, const float* __restrict__ outw,
    const float* __restrict__ outb, float* __restrict__ out)
{
  const int c = blockIdx.x*64 + (threadIdx.x & 63);
  const int tg = threadIdx.x >> 6;            // 0..3
  const int b = blockIdx.y;
  __shared__ float zs[SEQ];
  __shared__ float red[4][64];
  for (int t = threadIdx.x; t < SEQ; t += 256) zs[t] = Z[(size_t)b*SEQ + t];
  __syncthreads();
  float acc = 0.f;
  const int t0 = tg*384;
  for (int t = t0; t < t0+384; t++) acc += zs[t] * outw[(size_t)t*1024 + c];
  red[tg][threadIdx.x & 63] = acc;
  __syncthreads();
  if (tg == 0)
    out[(size_t)b*1024 + c] = red[0][c & 63] + red[1][c & 63] + red[2][c & 63] + red[3][c & 63] + outb[c];
}

extern "C" void kernel_launch(void* const* d_in, const int* in_sizes, int n_in,
                              void* d_out, int out_size, void* d_ws, size_t ws_size,
                              hipStream_t stream) {
  (void)in_sizes; (void)n_in;
  const float* mag  = (const float*)d_in[0];
  const float* syn  = (const float*)d_in[1];
  const float* magT = (const float*)d_in[2];
  const float* synT = (const float*)d_in[3];
  const float* se   = (const float*)d_in[4];
  const float* seT  = (const float*)d_in[5];
  const float* ln1s = (const float*)d_in[6];
  const float* ln1b = (const float*)d_in[7];
  const float* Wq   = (const float*)d_in[8];
  const float* bq   = (const float*)d_in[9];
  const float* Wk   = (const float*)d_in[10];
  const float* bk   = (const float*)d_in[11];
  const float* Wv   = (const float*)d_in[12];
  const float* bv   = (const float*)d_in[13];
  const float* Wo   = (const float*)d_in[14];
  const float* bo   = (const float*)d_in[15];
  const float* proj = (const float*)d_in[16];
  const float* ln2s = (const float*)d_in[17];
  const float* ln2b = (const float*)d_in[18];
  const float* W1   = (const float*)d_in[19];
  const float* b1   = (const float*)d_in[20];
  const float* W2   = (const float*)d_in[21];
  const float* b2   = (const float*)d_in[22];
  const float* fw   = (const float*)d_in[23];
  const float* fb   = (const float*)d_in[24];
  const float* outw = (const float*)d_in[25];
  const float* outb = (const float*)d_in[26];
  float* out = (float*)d_out;

  // ---- workspace layout (bytes) ----
  char* base = (char*)d_ws;
  const size_t PANEL = (size_t)RB*DM;
  size_t off = 0;
  u16*  Xh    = (u16*)(base + off);   off += PANEL*4;           // X bf16 (slot kept 4B-sized)
  float* Y1   = (float*)(base + off); off += PANEL*4;           // Y1 bf16 (half); aliases PART during attention
  u16*  Hb    = (u16*)(base + off);   off += PANEL*2;
  u16*  QKVb  = (u16*)(base + off);   off += PANEL*2*3;         // [RB][768]; also FFI [RB][512]
  u16*  Wts   = (u16*)(base + off);   off += (size_t)12*524288*2;
  u16*  CTXTb = (u16*)(base + off);   off += (size_t)256*4096*2;   // [bh][32][128] bf16
  float* KSb  = (float*)(base + off); off += (size_t)256*112*4;    // [bh][112] f32
  float* SVb  = (float*)(base + off); off += (size_t)NCH*256*32*4;
  float* STb  = (float*)(base + off); off += (size_t)NCH*256*4;    // per-chunk stab (f32)
  float* BQKV = (float*)(base + off); off += (size_t)12*QKVW*4;
  u16*  PROJB = (u16*)(base + off);   off += (size_t)12*112*32*2;
  float* Zb   = (float*)(base + off); off += (size_t)BSZ*SEQ*4;
  if (ws_size < off) {
    float v = 100000.0f + (float)(ws_size >> 20);
    sentinel_k<<<dim3((out_size+255)/256), 256, 0, stream>>>(out, out_size, v);
    return;
  }
  u16*  PARTb = (u16*)Y1;   // bf16 [NCH][256][MF][36] = 24.3 MB (Y1 dead during attention)
  u16*  Y1h   = (u16*)Y1;   // Y1 stored bf16 (25 MB of the 50 MB slot)
  const size_t WST = 524288;

  // ---- one-time prep: weights, biases, proj, zero ctxT/ksum pads ----
  wtrans_k<<<dim3(8,8,12),  256, 0, stream>>>(Wq, Wts + 0,      256, 256, WST);
  wtrans_k<<<dim3(8,8,12),  256, 0, stream>>>(Wk, Wts + 65536,  256, 256, WST);
  wtrans_k<<<dim3(8,8,12),  256, 0, stream>>>(Wv, Wts + 131072, 256, 256, WST);
  wtrans_k<<<dim3(8,8,12),  256, 0, stream>>>(Wo, Wts + 196608, 256, 256, WST);
  wtrans_k<<<dim3(16,8,12), 256, 0, stream>>>(W1, Wts + 262144, 256, 512, WST);
  wtrans_k<<<dim3(8,16,12), 256, 0, stream>>>(W2, Wts + 393216, 512, 256, WST);
  bpack_k<<<dim3(12), 256, 0, stream>>>(bq, bk, bv, BQKV);
  projcvt_k<<<dim3(12), 256, 0, stream>>>(proj, PROJB);
  zero_k<<<dim3((256*4096*2/4 + 255)/256), 256, 0, stream>>>((float*)CTXTb, 256*4096*2/4);
  zero_k<<<dim3((256*112 + 255)/256), 256, 0, stream>>>(KSb, 256*112);

  for (int s=0; s<2; s++){
    embed_k<<<dim3(RB/4), 256, 0, stream>>>(mag, syn, magT, synT, se, seT, Xh, s);
    for (int l=0; l<NL; l++){
      int wi = s*NL + l;
      const u16* Wqkvt = Wts + (size_t)wi*WST;          // [768][256] packed
      const u16* Wot = Wqkvt + 196608;
      const u16* W1t = Wqkvt + 262144;
      const u16* W2t = Wqkvt + 393216;
      const u16* pprojb = PROJB + (size_t)wi*112*32;

      lnb_k<<<dim3(RB/4), 256, 0, stream>>>(Xh, Hb, ln1s + (size_t)wi*DM, ln1b + (size_t)wi*DM);
      mgemm_k<<<dim3(6,384), 256, 0, stream>>>(Hb, Wqkvt, BQKV + (size_t)wi*QKVW, QKVb, nullptr, nullptr, 256, QKVW, 0);
      ctxacc_k<<<dim3(NH,BSZ,NCH), 256, 0, stream>>>(QKVb, pprojb, PARTb, SVb, STb);
      ctxred_k<<<dim3(MF*36), 256, 0, stream>>>(PARTb, SVb, STb, CTXTb, KSb);
      oattn_k<<<dim3(SEQ/256, NH, BSZ), 256, 0, stream>>>(QKVb, pprojb, CTXTb, KSb, Hb);
      // Y1 = bf16(X + O@Wo + bo)
      mgemm_k<<<dim3(2,384), 256, 0, stream>>>(Hb, Wot, bo + (size_t)wi*DM, Y1h, Xh, nullptr, 256, 256, 1);
      lnb_k<<<dim3(RB/4), 256, 0, stream>>>(Y1h, Hb, ln2s + (size_t)wi*DM, ln2b + (size_t)wi*DM);
      mgemm_k<<<dim3(4,384), 256, 0, stream>>>(Hb, W1t, b1 + (size_t)wi*512, QKVb, nullptr, nullptr, 256, 512, 2);
      // X = bf16(0.5*(X + Y1 + FFI@W2 + b2))
      mgemm_k<<<dim3(2,384), 256, 0, stream>>>(QKVb, W2t, b2 + (size_t)wi*DM, Xh, Xh, Y1h, 512, 256, 3);
    }
    zacc_k<<<dim3(RB/4), 256, 0, stream>>>(Xh, fw, fb, Zb, s);
  }

  out_k<<<dim3(16, BSZ), 256, 0, stream>>>(Zb, outw, outb, out);
}